// Round 5
// baseline (194.096 us; speedup 1.0000x reference)
//
#include <hip/hip_runtime.h>
#include <cstdint>

typedef __attribute__((ext_vector_type(8))) short short8;
typedef __attribute__((ext_vector_type(4))) short short4x;
typedef __attribute__((ext_vector_type(4))) float floatx4;

__device__ __forceinline__ unsigned short f2b(float f) {
    unsigned int u = __builtin_bit_cast(unsigned int, f);
    u += 0x7fffu + ((u >> 16) & 1u);   // round-to-nearest-even
    return (unsigned short)(u >> 16);
}
__device__ __forceinline__ float b2f(unsigned short s) {
    unsigned int u = ((unsigned int)s) << 16;
    return __builtin_bit_cast(float, u);
}

#define GLDS(g, l) __builtin_amdgcn_global_load_lds(                                   \
    (const __attribute__((address_space(1))) unsigned int*)(g),                        \
    (__attribute__((address_space(3))) unsigned int*)(l), 16, 0, 0)

// ---------------- elementwise fp32 -> bf16 ----------------
__global__ __launch_bounds__(256) void cvt_bf16_kernel(const float* __restrict__ in,
                                                       unsigned short* __restrict__ out, int n4) {
    int i = blockIdx.x * blockDim.x + threadIdx.x;
    if (i >= n4) return;
    float4 v = ((const float4*)in)[i];
    ushort4 o;
    o.x = f2b(v.x); o.y = f2b(v.y); o.z = f2b(v.z); o.w = f2b(v.w);
    ((ushort4*)out)[i] = o;
}

// ---------------- W[K,N] fp32 -> Wt[N,K] bf16 (tiled transpose) ----------------
__global__ __launch_bounds__(256) void transpose_cvt_kernel(const float* __restrict__ W,
                                                            unsigned short* __restrict__ Wt,
                                                            int K, int N) {
    __shared__ unsigned short tile[64][65];
    int k0 = blockIdx.x * 64, n0 = blockIdx.y * 64;
    for (int idx = threadIdx.x; idx < 64 * 64; idx += 256) {
        int i = idx >> 6, j = idx & 63;
        tile[j][i] = f2b(W[(size_t)(k0 + i) * N + n0 + j]);
    }
    __syncthreads();
    for (int idx = threadIdx.x; idx < 64 * 64; idx += 256) {
        int r = idx >> 6, c = idx & 63;
        Wt[(size_t)(n0 + r) * K + k0 + c] = tile[r][c];
    }
}

// ---------------- bf16 MFMA GEMM: C[M,N] = A[M,K] @ Bt[N,K]^T + bias ----------------
// Epilogue re-stages the 128x128 tile through LDS for coalesced vector stores.
// Blocks with colBase >= vSplit (the V third of qkv) store TRANSPOSED into
// vT[bh][d][s] instead (the qkv V-region is never read downstream).
template <int OUT_BF16>
__global__ __launch_bounds__(256) void gemm_bt_kernel(const unsigned short* __restrict__ A,
                                                      const unsigned short* __restrict__ Bt,
                                                      const float* __restrict__ bias,
                                                      void* __restrict__ Cv,
                                                      unsigned short* __restrict__ vTout,
                                                      int vSplit,
                                                      int M, int N, int K) {
    __shared__ __align__(16) unsigned char smem_raw[34816];
    unsigned short (*As)[32] = (unsigned short(*)[32])smem_raw;            // 8 KB
    unsigned short (*Bs)[32] = (unsigned short(*)[32])(smem_raw + 8192);   // 8 KB

    const int t = threadIdx.x;
    const int wave = t >> 6, lane = t & 63;
    const int quad = lane >> 4, l16 = lane & 15;
    const int rowBase = blockIdx.x * 128;
    const int colBase = blockIdx.y * 128;
    const int waveM = (wave >> 1) * 64;
    const int waveN = (wave & 1) * 64;

    floatx4 acc[4][4];
#pragma unroll
    for (int i = 0; i < 4; ++i)
#pragma unroll
        for (int j = 0; j < 4; ++j) acc[i][j] = (floatx4){0.f, 0.f, 0.f, 0.f};

    const int c0 = t, c1 = t + 256;
    const int r0 = c0 >> 2, cc0 = (c0 & 3) * 8;
    const int r1 = c1 >> 2, cc1 = (c1 & 3) * 8;

    const unsigned short* aBase = A + (size_t)rowBase * K;
    const unsigned short* bBase = Bt + (size_t)colBase * K;

    for (int k0 = 0; k0 < K; k0 += 32) {
        GLDS(aBase + (size_t)r0 * K + k0 + cc0, &As[r0][cc0]);
        GLDS(aBase + (size_t)r1 * K + k0 + cc1, &As[r1][cc1]);
        GLDS(bBase + (size_t)r0 * K + k0 + cc0, &Bs[r0][cc0]);
        GLDS(bBase + (size_t)r1 * K + k0 + cc1, &Bs[r1][cc1]);
        __syncthreads();

        short8 af[4], bf[4];
#pragma unroll
        for (int mi = 0; mi < 4; ++mi)
            af[mi] = *(const short8*)&As[waveM + mi * 16 + l16][quad * 8];
#pragma unroll
        for (int ni = 0; ni < 4; ++ni)
            bf[ni] = *(const short8*)&Bs[waveN + ni * 16 + l16][quad * 8];
#pragma unroll
        for (int mi = 0; mi < 4; ++mi)
#pragma unroll
            for (int ni = 0; ni < 4; ++ni)
                acc[mi][ni] = __builtin_amdgcn_mfma_f32_16x16x32_bf16(af[mi], bf[ni], acc[mi][ni], 0, 0, 0);
        __syncthreads();
    }
    // loop-end barrier guarantees all ds_reads retired; safe to reuse smem_raw.

    if (OUT_BF16 && colBase >= vSplit) {
        // ---- V mode: tile -> Ct[c][row] -> vT[bh][d][s] (coalesced 256B rows) ----
        unsigned short (*Ct)[136] = (unsigned short(*)[136])smem_raw;
#pragma unroll
        for (int ni = 0; ni < 4; ++ni) {
            int c = waveN + ni * 16 + l16;
            float bv = bias[colBase + c];
#pragma unroll
            for (int mi = 0; mi < 4; ++mi)
#pragma unroll
                for (int r = 0; r < 4; ++r)
                    Ct[c][waveM + mi * 16 + quad * 4 + r] = f2b(acc[mi][ni][r] + bv);
        }
        __syncthreads();
        const int b = rowBase >> 10, s0 = rowBase & 1023;
        const int vcol0 = colBase - vSplit;
#pragma unroll
        for (int p = 0; p < 8; ++p) {
            int idx = t + p * 256;
            int c = idx >> 4, ch = idx & 15;
            int hh = (vcol0 + c) >> 6, d = c & 63;
            short8 v = *(const short8*)&Ct[c][ch * 8];
            *(short8*)(vTout + ((size_t)(b * 16 + hh) * 64 + d) * 1024 + s0 + ch * 8) = v;
        }
    } else if (OUT_BF16) {
        // ---- bf16 row-major: tile -> Cs[row][col] -> coalesced short8 stores ----
        unsigned short (*Cs)[136] = (unsigned short(*)[136])smem_raw;
#pragma unroll
        for (int ni = 0; ni < 4; ++ni) {
            int c = waveN + ni * 16 + l16;
            float bv = bias[colBase + c];
#pragma unroll
            for (int mi = 0; mi < 4; ++mi)
#pragma unroll
                for (int r = 0; r < 4; ++r)
                    Cs[waveM + mi * 16 + quad * 4 + r][c] = f2b(acc[mi][ni][r] + bv);
        }
        __syncthreads();
        unsigned short* C = (unsigned short*)Cv;
#pragma unroll
        for (int p = 0; p < 8; ++p) {
            int idx = t + p * 256;
            int row = idx >> 4, ch = idx & 15;
            short8 v = *(const short8*)&Cs[row][ch * 8];
            *(short8*)(C + (size_t)(rowBase + row) * N + colBase + ch * 8) = v;
        }
    } else {
        // ---- fp32 row-major, two half-tile passes (LDS budget) ----
        float (*Cf)[132] = (float(*)[132])smem_raw;
        float* C = (float*)Cv;
#pragma unroll
        for (int half = 0; half < 2; ++half) {
            __syncthreads();
            if ((wave >> 1) == half) {
#pragma unroll
                for (int ni = 0; ni < 4; ++ni) {
                    int c = waveN + ni * 16 + l16;
                    float bv = bias[colBase + c];
#pragma unroll
                    for (int mi = 0; mi < 4; ++mi)
#pragma unroll
                        for (int r = 0; r < 4; ++r)
                            Cf[mi * 16 + quad * 4 + r][c] = acc[mi][ni][r] + bv;
                }
            }
            __syncthreads();
#pragma unroll
            for (int p = 0; p < 8; ++p) {
                int idx = t + p * 256;
                int row = idx >> 5, ch = idx & 31;
                float4 v = *(const float4*)&Cf[row][ch * 4];
                *(float4*)(C + (size_t)(rowBase + half * 64 + row) * N + colBase + ch * 4) = v;
            }
        }
    }
}

// ---------------- fused causal flash attention ----------------
// S^T = K.Q^T via 16x16x32 (A=K, B=Q); P^T stays in registers (C-layout == B-layout
// of 16x16x16bf16_1k); O^T = V^T.P^T. Paired q-tiles (p, 15-p) share the K/V stream.
__global__ __launch_bounds__(256) void attn_kernel(const unsigned short* __restrict__ qkv,
                                                   const unsigned short* __restrict__ vT,
                                                   unsigned short* __restrict__ aout) {
    __shared__ unsigned short Ks[2 * 64 * 64];
    __shared__ unsigned short Vs[2 * 64 * 64];
    __shared__ unsigned short Tb[4][16 * 72];

    const int p  = blockIdx.x;
    const int bh = blockIdx.y;
    const int b = bh >> 4, h = bh & 15;
    const int qb1 = p, qb2 = 15 - p;
    const int t = threadIdx.x;
    const int wave = t >> 6, lane = t & 63;
    const int quad = lane >> 4, l16 = lane & 15;
    const int h7 = l16 & 7;

    const size_t rowB = (size_t)b * 1024;
    const size_t hoff = (size_t)h * 64;
    const int qA0 = qb1 * 64 + wave * 16;
    const int qB0 = qb2 * 64 + wave * 16;

    short8 qfA[2], qfB[2];
#pragma unroll
    for (int kc = 0; kc < 2; ++kc) {
        short8 qa = *(const short8*)(qkv + (rowB + qA0 + l16) * 3072 + hoff + kc * 32 + quad * 8);
        short8 qb = *(const short8*)(qkv + (rowB + qB0 + l16) * 3072 + hoff + kc * 32 + quad * 8);
#pragma unroll
        for (int e = 0; e < 8; ++e) {
            qa[e] = (short)f2b(b2f((unsigned short)qa[e]) * 0.125f);
            qb[e] = (short)f2b(b2f((unsigned short)qb[e]) * 0.125f);
        }
        qfA[kc] = qa; qfB[kc] = qb;
    }

    const int lr = lane >> 3;
    const int sc8 = (lane & 7) * 8;
    const int gc8 = ((lane & 7) ^ lr) * 8;
    const unsigned short* kSrc = qkv + rowB * 3072 + hoff + 1024;
    const unsigned short* vSrc = vT + (size_t)bh * 65536;

    auto stage = [&](int kt, int bf) {
        const unsigned short* kp = kSrc + (size_t)kt * 64 * 3072;
        const unsigned short* vp = vSrc + kt * 64;
        int r0 = wave * 16 + lr, r1 = r0 + 8;
        GLDS(kp + (size_t)r0 * 3072 + gc8, &Ks[bf * 4096 + r0 * 64 + sc8]);
        GLDS(kp + (size_t)r1 * 3072 + gc8, &Ks[bf * 4096 + r1 * 64 + sc8]);
        GLDS(vp + (size_t)r0 * 1024 + gc8, &Vs[bf * 4096 + r0 * 64 + sc8]);
        GLDS(vp + (size_t)r1 * 1024 + gc8, &Vs[bf * 4096 + r1 * 64 + sc8]);
    };

    float lpA = 0.f, lpB = 0.f;
    floatx4 oA[4], oB[4];
#pragma unroll
    for (int ni = 0; ni < 4; ++ni) {
        oA[ni] = (floatx4){0.f, 0.f, 0.f, 0.f};
        oB[ni] = (floatx4){0.f, 0.f, 0.f, 0.f};
    }

    const int nT = qb2 + 1;
    stage(0, 0);

    for (int kt = 0; kt < nT; ++kt) {
        __syncthreads();
        if (kt + 1 < nT) stage(kt + 1, (kt + 1) & 1);
        const int kb = (kt & 1) * 4096;

        short8 kf[4][2];
#pragma unroll
        for (int jn = 0; jn < 4; ++jn)
#pragma unroll
            for (int kc = 0; kc < 2; ++kc)
                kf[jn][kc] = *(const short8*)&Ks[kb + (jn * 16 + l16) * 64 + (((kc * 4 + quad) ^ h7) * 8)];

        short4x vf[4][4];
#pragma unroll
        for (int ni = 0; ni < 4; ++ni)
#pragma unroll
            for (int jb = 0; jb < 4; ++jb)
                vf[ni][jb] = *(const short4x*)&Vs[kb + (ni * 16 + l16) * 64 +
                                                 (((jb * 2 + (quad >> 1)) ^ h7) * 8) + (quad & 1) * 4];

        auto qtile = [&](short8 (&qf)[2], floatx4 (&o)[4], float& lp, bool diag) {
            floatx4 s[4];
#pragma unroll
            for (int jn = 0; jn < 4; ++jn) s[jn] = (floatx4){0.f, 0.f, 0.f, 0.f};
#pragma unroll
            for (int jn = 0; jn < 4; ++jn)
#pragma unroll
                for (int kc = 0; kc < 2; ++kc)
                    s[jn] = __builtin_amdgcn_mfma_f32_16x16x32_bf16(kf[jn][kc], qf[kc], s[jn], 0, 0, 0);
            if (diag) {
                int ql = wave * 16 + l16;
#pragma unroll
                for (int jn = 0; jn < 4; ++jn)
#pragma unroll
                    for (int r = 0; r < 4; ++r)
                        if (jn * 16 + quad * 4 + r > ql) s[jn][r] = -1e30f;
            }
            short4x pb[4];
#pragma unroll
            for (int jb = 0; jb < 4; ++jb)
#pragma unroll
                for (int r = 0; r < 4; ++r) {
                    float pe = __expf(s[jb][r]);
                    lp += pe;
                    pb[jb][r] = (short)f2b(pe);
                }
#pragma unroll
            for (int jb = 0; jb < 4; ++jb)
#pragma unroll
                for (int ni = 0; ni < 4; ++ni)
                    o[ni] = __builtin_amdgcn_mfma_f32_16x16x16bf16_1k(vf[ni][jb], pb[jb], o[ni], 0, 0, 0);
        };

        qtile(qfB, oB, lpB, kt == qb2);
        if (kt <= qb1) qtile(qfA, oA, lpA, kt == qb1);
    }

    lpA += __shfl_xor(lpA, 16); lpA += __shfl_xor(lpA, 32);
    lpB += __shfl_xor(lpB, 16); lpB += __shfl_xor(lpB, 32);
    const float liA = 1.f / lpA, liB = 1.f / lpB;

    auto writeOut = [&](floatx4 (&o)[4], float li, int q0) {
#pragma unroll
        for (int ni = 0; ni < 4; ++ni)
#pragma unroll
            for (int r = 0; r < 4; ++r)
                Tb[wave][l16 * 72 + ni * 16 + quad * 4 + r] = f2b(o[ni][r] * li);
#pragma unroll
        for (int i = 0; i < 2; ++i) {
            int q = lane >> 2, c = (lane & 3) + 4 * i;
            short8 v = *(const short8*)&Tb[wave][q * 72 + c * 8];
            *(short8*)(aout + (rowB + q0 + q) * 1024 + hoff + c * 8) = v;
        }
    };
    writeOut(oA, liA, qA0);
    writeOut(oB, liB, qB0);
}

extern "C" void kernel_launch(void* const* d_in, const int* in_sizes, int n_in,
                              void* d_out, int out_size, void* d_ws, size_t ws_size,
                              hipStream_t stream) {
    const float* x  = (const float*)d_in[0];
    const float* w1 = (const float*)d_in[1];
    const float* b1 = (const float*)d_in[2];
    const float* w2 = (const float*)d_in[3];
    const float* b2 = (const float*)d_in[4];
    float* out = (float*)d_out;

    unsigned short* xb   = (unsigned short*)d_ws;              // 8 MB
    unsigned short* w1t  = xb  + (size_t)4096 * 1024;          // 6 MB  [3072,1024]
    unsigned short* w2t  = w1t + (size_t)3072 * 1024;          // 2 MB  [1024,1024]
    unsigned short* qkv  = w2t + (size_t)1024 * 1024;          // 24 MB [4096,3072] (V third unused)
    unsigned short* attn = qkv + (size_t)4096 * 3072;          // 8 MB  [4096,1024]
    unsigned short* vTb  = attn + (size_t)4096 * 1024;         // 8 MB  [64,64,1024]

    cvt_bf16_kernel<<<4096, 256, 0, stream>>>(x, xb, 4096 * 1024 / 4);
    transpose_cvt_kernel<<<dim3(16, 48), 256, 0, stream>>>(w1, w1t, 1024, 3072);
    transpose_cvt_kernel<<<dim3(16, 16), 256, 0, stream>>>(w2, w2t, 1024, 1024);

    gemm_bt_kernel<1><<<dim3(32, 24), 256, 0, stream>>>(xb, w1t, b1, qkv, vTb, 2048,
                                                        4096, 3072, 1024);
    attn_kernel<<<dim3(8, 64), 256, 0, stream>>>(qkv, vTb, attn);
    gemm_bt_kernel<0><<<dim3(32, 8), 256, 0, stream>>>(attn, w2t, b2, out, nullptr, 1 << 30,
                                                       4096, 1024, 1024);
}

// Round 6
// 166.298 us; speedup vs baseline: 1.1672x; 1.1672x over previous
//
#include <hip/hip_runtime.h>
#include <cstdint>

typedef __attribute__((ext_vector_type(8))) short short8;
typedef __attribute__((ext_vector_type(4))) short short4x;
typedef __attribute__((ext_vector_type(4))) float floatx4;

__device__ __forceinline__ unsigned short f2b(float f) {
    unsigned int u = __builtin_bit_cast(unsigned int, f);
    u += 0x7fffu + ((u >> 16) & 1u);   // round-to-nearest-even
    return (unsigned short)(u >> 16);
}
__device__ __forceinline__ float b2f(unsigned short s) {
    unsigned int u = ((unsigned int)s) << 16;
    return __builtin_bit_cast(float, u);
}

#define GLDS(g, l) __builtin_amdgcn_global_load_lds(                                   \
    (const __attribute__((address_space(1))) unsigned int*)(g),                        \
    (__attribute__((address_space(3))) unsigned int*)(l), 16, 0, 0)

// ---------------- fused prep: x->bf16 cvt + both weight transposes ----------------
__global__ __launch_bounds__(256) void prep_kernel(const float* __restrict__ x,
                                                   unsigned short* __restrict__ xb,
                                                   const float* __restrict__ w1,
                                                   unsigned short* __restrict__ w1t,
                                                   const float* __restrict__ w2,
                                                   unsigned short* __restrict__ w2t) {
    __shared__ unsigned short tile[64][65];
    const int b = blockIdx.x, t = threadIdx.x;
    if (b < 1024) {
        // cvt: 4096*1024 floats = 1,048,576 float4s, grid-stride over 1024 blocks
        for (int i = b * 256 + t; i < 1048576; i += 262144) {
            float4 v = ((const float4*)x)[i];
            ushort4 o;
            o.x = f2b(v.x); o.y = f2b(v.y); o.z = f2b(v.z); o.w = f2b(v.w);
            ((ushort4*)xb)[i] = o;
        }
        return;
    }
    const float* W; unsigned short* Wt; int K, N, kb, nb;
    if (b < 1792) { W = w1; Wt = w1t; K = 1024; N = 3072; kb = (b - 1024) & 15; nb = (b - 1024) >> 4; }
    else          { W = w2; Wt = w2t; K = 1024; N = 1024; kb = (b - 1792) & 15; nb = (b - 1792) >> 4; }
    const int k0 = kb * 64, n0 = nb * 64;
    for (int idx = t; idx < 64 * 64; idx += 256) {
        int i = idx >> 6, j = idx & 63;
        tile[j][i] = f2b(W[(size_t)(k0 + i) * N + n0 + j]);
    }
    __syncthreads();
    for (int idx = t; idx < 64 * 64; idx += 256) {
        int r = idx >> 6, c = idx & 63;
        Wt[(size_t)(n0 + r) * K + k0 + c] = tile[r][c];
    }
}

// ---------------- V slice of qkv -> vT[bh][d][s] (bf16, conflict-free) ----------------
__global__ __launch_bounds__(256) void vtrans_kernel(const unsigned short* __restrict__ qkv,
                                                     unsigned short* __restrict__ vT) {
    __shared__ unsigned short tile[64][65];
    const int st = blockIdx.x * 64;
    const int bh = blockIdx.y;
    const int b = bh >> 4, h = bh & 15;
    const int t = threadIdx.x;
#pragma unroll
    for (int p = 0; p < 2; ++p) {
        int c = t + p * 256;
        int srow = c >> 3, dcol = (c & 7) * 8;
        short8 v = *(const short8*)(qkv + (size_t)(b * 1024 + st + srow) * 3072 + 2048 + h * 64 + dcol);
#pragma unroll
        for (int e = 0; e < 8; ++e) tile[dcol + e][srow] = (unsigned short)v[e];
    }
    __syncthreads();
#pragma unroll
    for (int p = 0; p < 2; ++p) {
        int c = t + p * 256;
        int drow = c >> 3, scol = (c & 7) * 8;
        short8 v;
#pragma unroll
        for (int e = 0; e < 8; ++e) v[e] = (short)tile[drow][scol + e];
        *(short8*)(vT + ((size_t)bh * 64 + drow) * 1024 + st + scol) = v;
    }
}

// ---------------- bf16 MFMA GEMM 128x128, GLDS double-buffer, 1 barrier/iter ----------------
__global__ __launch_bounds__(256) void gemm_bt_kernel(const unsigned short* __restrict__ A,
                                                      const unsigned short* __restrict__ Bt,
                                                      const float* __restrict__ bias,
                                                      unsigned short* __restrict__ C,
                                                      int M, int N, int K) {
    __shared__ unsigned short As[2][128][32];   // 16 KB
    __shared__ unsigned short Bs[2][128][32];   // 16 KB

    const int t = threadIdx.x;
    const int wave = t >> 6, lane = t & 63;
    const int quad = lane >> 4, l16 = lane & 15;
    const int rowBase = blockIdx.x * 128;
    const int colBase = blockIdx.y * 128;
    const int waveM = (wave >> 1) * 64;
    const int waveN = (wave & 1) * 64;

    floatx4 acc[4][4];
#pragma unroll
    for (int i = 0; i < 4; ++i)
#pragma unroll
        for (int j = 0; j < 4; ++j) acc[i][j] = (floatx4){0.f, 0.f, 0.f, 0.f};

    const int r0 = t >> 2, cc0 = (t & 3) * 8;
    const int r1 = 64 + (t >> 2);
    const unsigned short* aBase = A + (size_t)rowBase * K;
    const unsigned short* bBase = Bt + (size_t)colBase * K;

    auto stage = [&](int kk, int bf) {
        const int k0 = kk * 32;
        GLDS(aBase + (size_t)r0 * K + k0 + cc0, &As[bf][r0][cc0]);
        GLDS(aBase + (size_t)r1 * K + k0 + cc0, &As[bf][r1][cc0]);
        GLDS(bBase + (size_t)r0 * K + k0 + cc0, &Bs[bf][r0][cc0]);
        GLDS(bBase + (size_t)r1 * K + k0 + cc0, &Bs[bf][r1][cc0]);
    };

    const int nIter = K >> 5;
    stage(0, 0);

    for (int kk = 0; kk < nIter; ++kk) {
        __syncthreads();                                   // tile kk landed (in flight a full iter)
        if (kk + 1 < nIter) stage(kk + 1, (kk + 1) & 1);   // prefetch next into other buffer
        const int buf = kk & 1;

        short8 af[4], bf[4];
#pragma unroll
        for (int mi = 0; mi < 4; ++mi)
            af[mi] = *(const short8*)&As[buf][waveM + mi * 16 + l16][quad * 8];
#pragma unroll
        for (int ni = 0; ni < 4; ++ni)
            bf[ni] = *(const short8*)&Bs[buf][waveN + ni * 16 + l16][quad * 8];
#pragma unroll
        for (int mi = 0; mi < 4; ++mi)
#pragma unroll
            for (int ni = 0; ni < 4; ++ni)
                acc[mi][ni] = __builtin_amdgcn_mfma_f32_16x16x32_bf16(af[mi], bf[ni], acc[mi][ni], 0, 0, 0);
    }

#pragma unroll
    for (int mi = 0; mi < 4; ++mi)
#pragma unroll
        for (int ni = 0; ni < 4; ++ni) {
            int col = colBase + waveN + ni * 16 + l16;
            float bv = bias[col];
#pragma unroll
            for (int r = 0; r < 4; ++r) {
                int row = rowBase + waveM + mi * 16 + quad * 4 + r;
                C[(size_t)row * N + col] = f2b(acc[mi][ni][r] + bv);
            }
        }
}

// ---------------- fp32-out GEMM 64x64 tiles (grid 1024 = 4 blocks/CU), GLDS dbuf ----------------
__global__ __launch_bounds__(256) void gemm2_kernel(const unsigned short* __restrict__ A,
                                                    const unsigned short* __restrict__ Bt,
                                                    const float* __restrict__ bias,
                                                    float* __restrict__ C,
                                                    int M, int N, int K) {
    __shared__ unsigned short As[2][64][32];   // 8 KB
    __shared__ unsigned short Bs[2][64][32];   // 8 KB

    const int t = threadIdx.x;
    const int wave = t >> 6, lane = t & 63;
    const int quad = lane >> 4, l16 = lane & 15;
    const int rowBase = blockIdx.x * 64;
    const int colBase = blockIdx.y * 64;
    const int waveM = (wave >> 1) * 32;
    const int waveN = (wave & 1) * 32;

    floatx4 acc[2][2];
#pragma unroll
    for (int i = 0; i < 2; ++i)
#pragma unroll
        for (int j = 0; j < 2; ++j) acc[i][j] = (floatx4){0.f, 0.f, 0.f, 0.f};

    const int r0 = t >> 2, cc0 = (t & 3) * 8;
    const unsigned short* aBase = A + (size_t)rowBase * K;
    const unsigned short* bBase = Bt + (size_t)colBase * K;

    auto stage = [&](int kk, int bf) {
        const int k0 = kk * 32;
        GLDS(aBase + (size_t)r0 * K + k0 + cc0, &As[bf][r0][cc0]);
        GLDS(bBase + (size_t)r0 * K + k0 + cc0, &Bs[bf][r0][cc0]);
    };

    const int nIter = K >> 5;
    stage(0, 0);

    for (int kk = 0; kk < nIter; ++kk) {
        __syncthreads();
        if (kk + 1 < nIter) stage(kk + 1, (kk + 1) & 1);
        const int buf = kk & 1;

        short8 af[2], bf[2];
#pragma unroll
        for (int mi = 0; mi < 2; ++mi)
            af[mi] = *(const short8*)&As[buf][waveM + mi * 16 + l16][quad * 8];
#pragma unroll
        for (int ni = 0; ni < 2; ++ni)
            bf[ni] = *(const short8*)&Bs[buf][waveN + ni * 16 + l16][quad * 8];
#pragma unroll
        for (int mi = 0; mi < 2; ++mi)
#pragma unroll
            for (int ni = 0; ni < 2; ++ni)
                acc[mi][ni] = __builtin_amdgcn_mfma_f32_16x16x32_bf16(af[mi], bf[ni], acc[mi][ni], 0, 0, 0);
    }

#pragma unroll
    for (int mi = 0; mi < 2; ++mi)
#pragma unroll
        for (int ni = 0; ni < 2; ++ni) {
            int col = colBase + waveN + ni * 16 + l16;
            float bv = bias[col];
#pragma unroll
            for (int r = 0; r < 4; ++r) {
                int row = rowBase + waveM + mi * 16 + quad * 4 + r;
                C[(size_t)row * N + col] = acc[mi][ni][r] + bv;
            }
        }
}

// ---------------- fused causal flash attention (validated R4 structure) ----------------
__global__ __launch_bounds__(256) void attn_kernel(const unsigned short* __restrict__ qkv,
                                                   const unsigned short* __restrict__ vT,
                                                   unsigned short* __restrict__ aout) {
    __shared__ unsigned short Ks[2 * 64 * 64];
    __shared__ unsigned short Vs[2 * 64 * 64];
    __shared__ unsigned short Tb[4][16 * 72];

    const int p  = blockIdx.x;
    const int bh = blockIdx.y;
    const int b = bh >> 4, h = bh & 15;
    const int qb1 = p, qb2 = 15 - p;
    const int t = threadIdx.x;
    const int wave = t >> 6, lane = t & 63;
    const int quad = lane >> 4, l16 = lane & 15;
    const int h7 = l16 & 7;

    const size_t rowB = (size_t)b * 1024;
    const size_t hoff = (size_t)h * 64;
    const int qA0 = qb1 * 64 + wave * 16;
    const int qB0 = qb2 * 64 + wave * 16;

    short8 qfA[2], qfB[2];
#pragma unroll
    for (int kc = 0; kc < 2; ++kc) {
        short8 qa = *(const short8*)(qkv + (rowB + qA0 + l16) * 3072 + hoff + kc * 32 + quad * 8);
        short8 qb = *(const short8*)(qkv + (rowB + qB0 + l16) * 3072 + hoff + kc * 32 + quad * 8);
#pragma unroll
        for (int e = 0; e < 8; ++e) {
            qa[e] = (short)f2b(b2f((unsigned short)qa[e]) * 0.125f);
            qb[e] = (short)f2b(b2f((unsigned short)qb[e]) * 0.125f);
        }
        qfA[kc] = qa; qfB[kc] = qb;
    }

    const int lr = lane >> 3;
    const int sc8 = (lane & 7) * 8;
    const int gc8 = ((lane & 7) ^ lr) * 8;
    const unsigned short* kSrc = qkv + rowB * 3072 + hoff + 1024;
    const unsigned short* vSrc = vT + (size_t)bh * 65536;

    auto stage = [&](int kt, int bf) {
        const unsigned short* kp = kSrc + (size_t)kt * 64 * 3072;
        const unsigned short* vp = vSrc + kt * 64;
        int r0 = wave * 16 + lr, r1 = r0 + 8;
        GLDS(kp + (size_t)r0 * 3072 + gc8, &Ks[bf * 4096 + r0 * 64 + sc8]);
        GLDS(kp + (size_t)r1 * 3072 + gc8, &Ks[bf * 4096 + r1 * 64 + sc8]);
        GLDS(vp + (size_t)r0 * 1024 + gc8, &Vs[bf * 4096 + r0 * 64 + sc8]);
        GLDS(vp + (size_t)r1 * 1024 + gc8, &Vs[bf * 4096 + r1 * 64 + sc8]);
    };

    float lpA = 0.f, lpB = 0.f;
    floatx4 oA[4], oB[4];
#pragma unroll
    for (int ni = 0; ni < 4; ++ni) {
        oA[ni] = (floatx4){0.f, 0.f, 0.f, 0.f};
        oB[ni] = (floatx4){0.f, 0.f, 0.f, 0.f};
    }

    const int nT = qb2 + 1;
    stage(0, 0);

    for (int kt = 0; kt < nT; ++kt) {
        __syncthreads();
        if (kt + 1 < nT) stage(kt + 1, (kt + 1) & 1);
        const int kb = (kt & 1) * 4096;

        short8 kf[4][2];
#pragma unroll
        for (int jn = 0; jn < 4; ++jn)
#pragma unroll
            for (int kc = 0; kc < 2; ++kc)
                kf[jn][kc] = *(const short8*)&Ks[kb + (jn * 16 + l16) * 64 + (((kc * 4 + quad) ^ h7) * 8)];

        short4x vf[4][4];
#pragma unroll
        for (int ni = 0; ni < 4; ++ni)
#pragma unroll
            for (int jb = 0; jb < 4; ++jb)
                vf[ni][jb] = *(const short4x*)&Vs[kb + (ni * 16 + l16) * 64 +
                                                 (((jb * 2 + (quad >> 1)) ^ h7) * 8) + (quad & 1) * 4];

        auto qtile = [&](short8 (&qf)[2], floatx4 (&o)[4], float& lp, bool diag) {
            floatx4 s[4];
#pragma unroll
            for (int jn = 0; jn < 4; ++jn) s[jn] = (floatx4){0.f, 0.f, 0.f, 0.f};
#pragma unroll
            for (int jn = 0; jn < 4; ++jn)
#pragma unroll
                for (int kc = 0; kc < 2; ++kc)
                    s[jn] = __builtin_amdgcn_mfma_f32_16x16x32_bf16(kf[jn][kc], qf[kc], s[jn], 0, 0, 0);
            if (diag) {
                int ql = wave * 16 + l16;
#pragma unroll
                for (int jn = 0; jn < 4; ++jn)
#pragma unroll
                    for (int r = 0; r < 4; ++r)
                        if (jn * 16 + quad * 4 + r > ql) s[jn][r] = -1e30f;
            }
            short4x pb[4];
#pragma unroll
            for (int jb = 0; jb < 4; ++jb)
#pragma unroll
                for (int r = 0; r < 4; ++r) {
                    float pe = __expf(s[jb][r]);
                    lp += pe;
                    pb[jb][r] = (short)f2b(pe);
                }
#pragma unroll
            for (int jb = 0; jb < 4; ++jb)
#pragma unroll
                for (int ni = 0; ni < 4; ++ni)
                    o[ni] = __builtin_amdgcn_mfma_f32_16x16x16bf16_1k(vf[ni][jb], pb[jb], o[ni], 0, 0, 0);
        };

        qtile(qfB, oB, lpB, kt == qb2);
        if (kt <= qb1) qtile(qfA, oA, lpA, kt == qb1);
    }

    lpA += __shfl_xor(lpA, 16); lpA += __shfl_xor(lpA, 32);
    lpB += __shfl_xor(lpB, 16); lpB += __shfl_xor(lpB, 32);
    const float liA = 1.f / lpA, liB = 1.f / lpB;

    auto writeOut = [&](floatx4 (&o)[4], float li, int q0) {
#pragma unroll
        for (int ni = 0; ni < 4; ++ni)
#pragma unroll
            for (int r = 0; r < 4; ++r)
                Tb[wave][l16 * 72 + ni * 16 + quad * 4 + r] = f2b(o[ni][r] * li);
#pragma unroll
        for (int i = 0; i < 2; ++i) {
            int q = lane >> 2, c = (lane & 3) + 4 * i;
            short8 v = *(const short8*)&Tb[wave][q * 72 + c * 8];
            *(short8*)(aout + (rowB + q0 + q) * 1024 + hoff + c * 8) = v;
        }
    };
    writeOut(oA, liA, qA0);
    writeOut(oB, liB, qB0);
}

extern "C" void kernel_launch(void* const* d_in, const int* in_sizes, int n_in,
                              void* d_out, int out_size, void* d_ws, size_t ws_size,
                              hipStream_t stream) {
    const float* x  = (const float*)d_in[0];
    const float* w1 = (const float*)d_in[1];
    const float* b1 = (const float*)d_in[2];
    const float* w2 = (const float*)d_in[3];
    const float* b2 = (const float*)d_in[4];
    float* out = (float*)d_out;

    unsigned short* xb   = (unsigned short*)d_ws;              // 8 MB
    unsigned short* w1t  = xb  + (size_t)4096 * 1024;          // 6 MB  [3072,1024]
    unsigned short* w2t  = w1t + (size_t)3072 * 1024;          // 2 MB  [1024,1024]
    unsigned short* qkv  = w2t + (size_t)1024 * 1024;          // 24 MB [4096,3072]
    unsigned short* attn = qkv + (size_t)4096 * 3072;          // 8 MB  [4096,1024]
    unsigned short* vTb  = attn + (size_t)4096 * 1024;         // 8 MB  [64,64,1024]

    prep_kernel<<<2048, 256, 0, stream>>>(x, xb, w1, w1t, w2, w2t);
    gemm_bt_kernel<<<dim3(32, 24), 256, 0, stream>>>(xb, w1t, b1, qkv, 4096, 3072, 1024);
    vtrans_kernel<<<dim3(16, 64), 256, 0, stream>>>(qkv, vTb);
    attn_kernel<<<dim3(8, 64), 256, 0, stream>>>(qkv, vTb, attn);
    gemm2_kernel<<<dim3(64, 16), 256, 0, stream>>>(attn, w2t, b2, out, 4096, 1024, 1024);
}